// Round 4
// baseline (400.790 us; speedup 1.0000x reference)
//
#include <hip/hip_runtime.h>
#include <cstddef>
#include <cstdint>

#define NTOK 4096
#define NB_  8

// 0.25 (=1/sqrt(Cq)) * log2(e): folded into q so flash can use raw exp2.
#define QSCALE 0.36067376022224085f

typedef float f32x4  __attribute__((ext_vector_type(4)));
typedef float f32x16 __attribute__((ext_vector_type(16)));
typedef short s16x8  __attribute__((ext_vector_type(8)));

#if __has_builtin(__builtin_amdgcn_exp2f)
#define EXP2F(x) __builtin_amdgcn_exp2f(x)
#else
#define EXP2F(x) exp2f(x)
#endif

static __device__ __forceinline__ unsigned short f2bf(float f) {
    unsigned u = __float_as_uint(f);
    unsigned r = (u + 0x7FFFu + ((u >> 16) & 1u)) >> 16;
    return (unsigned short)r;
}

// 2 f32 -> packed bf16 pair (low half = a), RNE.
static __device__ __forceinline__ unsigned cvtpkbf(float a, float b) {
    unsigned r;
    asm("v_cvt_pk_bf16_f32 %0, %1, %2" : "=v"(r) : "v"(a), "v"(b));
    return r;
}

// v_permlane32_swap_b32: ret.x = [a(lanes0-31) | b(lanes0-31)],
//                        ret.y = [a(lanes32-63) | b(lanes32-63)].
static __device__ __forceinline__ uint2 plswap32(unsigned a, unsigned b) {
#if __has_builtin(__builtin_amdgcn_permlane32_swap)
    auto r = __builtin_amdgcn_permlane32_swap((int)a, (int)b, false, false);
    return make_uint2((unsigned)r[0], (unsigned)r[1]);
#else
    const int xa = (((int)threadIdx.x & 63) ^ 32) << 2;
    const unsigned pa = (unsigned)__builtin_amdgcn_ds_bpermute(xa, (int)a);
    const unsigned pb = (unsigned)__builtin_amdgcn_ds_bpermute(xa, (int)b);
    const bool hi = (threadIdx.x & 32) != 0;
    return make_uint2(hi ? pb : a, hi ? b : pa);
#endif
}

// async global(16B/lane) -> LDS(base + lane*16), wave-level
static __device__ __forceinline__ void gload16(const void* g, void* l) {
    __builtin_amdgcn_global_load_lds(
        (const __attribute__((address_space(1))) unsigned int*)g,
        (__attribute__((address_space(3))) unsigned int*)l, 16, 0, 0);
}

// ---------------- P0: weights fp32 -> bf16 ----------------
__global__ __launch_bounds__(256) void wcvt_kernel(
    const float* __restrict__ Wq, const float* __restrict__ Wk, const float* __restrict__ Wv,
    unsigned short* __restrict__ wvb, unsigned short* __restrict__ wqb,
    unsigned short* __restrict__ wkb)
{
    int i = blockIdx.x * 256 + threadIdx.x;  // 0..20479
    if (i < 16384)      wvb[i]         = f2bf(Wv[i]);
    else if (i < 18432) wqb[i - 16384] = f2bf(Wq[i - 16384]);
    else                wkb[i - 18432] = f2bf(Wk[i - 18432]);
}

// ---------------- P1: fused transpose + projections ----------------
// Flat grid 512 blocks; b = blk & 7 pins each batch to one XCD so outputs land
// in the L2 flash will read. V is written in flash's fragment-major layout:
// v3[b][jt=j>>6][s=(j>>4)&3][h=(j>>3)&1][c][e=j&7]
// MFMA operand order chosen so each thread's 4 accumulator elements map to
// CONSECUTIVE addresses -> all stores are 8B uint2, wave-coalesced.
__global__ __launch_bounds__(256) void proj_kernel(
    const float* __restrict__ x,
    const unsigned short* __restrict__ wvb, const unsigned short* __restrict__ wqb,
    const unsigned short* __restrict__ wkb,
    const float* __restrict__ bq, const float* __restrict__ bk, const float* __restrict__ bv,
    unsigned short* __restrict__ qb, unsigned short* __restrict__ kb,
    unsigned short* __restrict__ vt)
{
    __shared__ float lt[128][68];   // [c][n0..63], padded rows (16B-aligned stride)
    const int t = threadIdx.x;
    const int w = t >> 6, lane = t & 63;
    const int c16 = lane & 15, g16 = lane >> 4;
    const int b  = blockIdx.x & 7;
    const int n0 = (blockIdx.x >> 3) * 64;

    // stage x tile: 128 rows x 64 floats
    {
        const int n4 = t & 15;
#pragma unroll
        for (int pass = 0; pass < 8; ++pass) {
            const int c = (t >> 4) + 16 * pass;
            const float4 val = ((const float4*)(x + ((size_t)b * 128 + c) * NTOK + n0))[n4];
            *(float4*)&lt[c][n4 * 4] = val;
        }
    }
    __syncthreads();

    // xf fragments for this wave's 16 tokens (token = n0 + 16w + c16)
    // A-frag view: A[m=token(c16)][k=ch 8g16+e]; B-frag view: B[k=ch][n=token(c16)]
    const int nl = 16 * w + c16;
    s16x8 xf[4];
#pragma unroll
    for (int kc = 0; kc < 4; ++kc) {
        unsigned rr[8];
#pragma unroll
        for (int i = 0; i < 8; ++i) {
            const unsigned u = __float_as_uint(lt[32 * kc + 8 * g16 + i][nl]);
            rr[i] = u + 0x7FFFu + ((u >> 16) & 1u);
        }
        union { s16x8 v; unsigned u[4]; } cvt;
#pragma unroll
        for (int d = 0; d < 4; ++d)
            cvt.u[d] = __builtin_amdgcn_perm(rr[2 * d + 1], rr[2 * d], 0x07060302u);
        xf[kc] = cvt.v;
    }

    // ---- V = Wv * X  (fragment-major for flash) ----
    // mfma(xf, wf): D[m=token 4g16+r][n=c_out 16mt+c16].
    // token j = n0 + 16w + 4g16 + r: s=w, h=g16>>1, e=4(g16&1)+r -> r contiguous.
    unsigned short* vwp = vt + (size_t)b * (NTOK * 128) +
                          (size_t)(((n0 >> 6) * 8) + 2 * w + (g16 >> 1)) * 1024 + 4 * (g16 & 1);
#pragma unroll
    for (int mt = 0; mt < 8; ++mt) {
        f32x4 acc = {0.f, 0.f, 0.f, 0.f};
#pragma unroll
        for (int kc = 0; kc < 4; ++kc) {
            const s16x8 wf = *(const s16x8*)(wvb + (size_t)(16 * mt + c16) * 128 + 32 * kc + 8 * g16);
            acc = __builtin_amdgcn_mfma_f32_16x16x32_bf16(xf[kc], wf, acc, 0, 0, 0);
        }
        const float bvv = bv[16 * mt + c16];
        uint2 pkv;
        pkv.x = cvtpkbf(acc[0] + bvv, acc[1] + bvv);
        pkv.y = cvtpkbf(acc[2] + bvv, acc[3] + bvv);
        *(uint2*)(vwp + (size_t)(16 * mt + c16) * 8) = pkv;
    }
    // ---- Q, K ----
    // mfma(wqf, xf): D[m=qch 4g16+r][n=token c16] -> 4 consecutive qch per thread.
    f32x4 aq = {0.f, 0.f, 0.f, 0.f}, ak = {0.f, 0.f, 0.f, 0.f};
#pragma unroll
    for (int kc = 0; kc < 4; ++kc) {
        const s16x8 wqf = *(const s16x8*)(wqb + (size_t)c16 * 128 + 32 * kc + 8 * g16);
        const s16x8 wkf = *(const s16x8*)(wkb + (size_t)c16 * 128 + 32 * kc + 8 * g16);
        aq = __builtin_amdgcn_mfma_f32_16x16x32_bf16(wqf, xf[kc], aq, 0, 0, 0);
        ak = __builtin_amdgcn_mfma_f32_16x16x32_bf16(wkf, xf[kc], ak, 0, 0, 0);
    }
    const float4 bq4 = *(const float4*)(bq + 4 * g16);
    const float4 bk4 = *(const float4*)(bk + 4 * g16);
    const int n = n0 + 16 * w + c16;
    uint2 pq, pkk;
    pq.x  = cvtpkbf(QSCALE * (aq[0] + bq4.x), QSCALE * (aq[1] + bq4.y));
    pq.y  = cvtpkbf(QSCALE * (aq[2] + bq4.z), QSCALE * (aq[3] + bq4.w));
    pkk.x = cvtpkbf(ak[0] + bk4.x, ak[1] + bk4.y);
    pkk.y = cvtpkbf(ak[2] + bk4.z, ak[3] + bk4.w);
    *(uint2*)(qb + ((size_t)b * NTOK + n) * 16 + 4 * g16) = pq;
    *(uint2*)(kb + ((size_t)b * NTOK + n) * 16 + 4 * g16) = pkk;
}

// ---------------- P2: flash attention, LDS-shared K/V tiles ----------------
// Grid 256 blocks (= 1/CU): b = blk & 7 (XCD-pinned batch), m-tile = blk>>3 (128 q rows).
// 8 waves = (mw 0..3) x (jw 0..1): wave owns 32 q-rows (mrow = m0+32mw) and the
// jw-th 32-j half of every staged 64-j tile. V/K tiles staged via async
// global_load_lds, double-buffered; all 8 waves share each tile.
// r3 lesson: keeping all 8 V fragments live forced the allocator to spill the
// O accumulator (256B/thread) to scratch EVERY iteration -> 2.15 GB of HBM
// writes -> write-roofline-bound at 306us. V fragments are now loaded from LDS
// immediately before each MFMA so only ~1-2 are live at once.
__global__ __launch_bounds__(512, 2) void flash_kernel(
    const unsigned short* __restrict__ qb, const unsigned short* __restrict__ kb,
    const unsigned short* __restrict__ vt, const float* __restrict__ x,
    const float* __restrict__ gamma, float* __restrict__ out)
{
    __shared__ __align__(16) unsigned char smem[37888];
    unsigned short* sV = (unsigned short*)smem;              // [2][8192] (16KB each)
    unsigned short* sK = (unsigned short*)(smem + 32768);    // [2][1024] (2KB each)
    float* lb = (float*)(smem + 36864);                      // [8][32]
    float* cO = (float*)smem;                                // combine alias [4][64][33]

    const int t = threadIdx.x;
    const int w = t >> 6, lane = t & 63;
    const int m31 = lane & 31, h = lane >> 5;
    const int mw = w >> 1, jw = w & 1;
    const int b  = blockIdx.x & 7;
    const int m0 = (blockIdx.x >> 3) * 128;
    const int mrow = m0 + 32 * mw;

    const unsigned short* vtile0 = vt + (size_t)b * (NTOK * 128);  // 16KB per jt tile, contiguous
    const unsigned short* ktile0 = kb + (size_t)b * (NTOK * 16);   // 2KB per jt tile, contiguous

    // Q B-frag: B[k=ch 8h+e][n=m31]; scale (incl. log2e) pre-folded into qb.
    const s16x8 qf = *(const s16x8*)(qb + ((size_t)b * NTOK + mrow + m31) * 16 + 8 * h);

    f32x16 O[4];
#pragma unroll
    for (int ct = 0; ct < 4; ++ct)
#pragma unroll
        for (int r = 0; r < 16; ++r) O[ct][r] = 0.f;
    float la0 = 0.f, la1 = 0.f, la2 = 0.f, la3 = 0.f;

    // stage tile jt_ into buffer d: V 16KB (2 calls/wave), K 2KB (waves 0,1)
#define STAGE(d, jt_) do {                                                          \
        const unsigned short* vs_ = vtile0 + (size_t)(jt_) * 8192 + w * 1024 + lane * 8; \
        gload16(vs_,       smem + (d) * 16384 + w * 2048);                          \
        gload16(vs_ + 512, smem + (d) * 16384 + w * 2048 + 1024);                   \
        if (w < 2) {                                                                \
            const unsigned short* ks_ = ktile0 + (size_t)(jt_) * 1024 + w * 512 + lane * 8; \
            gload16(ks_, smem + 32768 + (d) * 2048 + w * 1024);                     \
        }                                                                           \
    } while (0)

    STAGE(0, 0);
    __syncthreads();   // drains vmcnt -> tile 0 resident

    int cur = 0;
    for (int jt = 0; jt < 64; ++jt) {
        if (jt < 63) STAGE(cur ^ 1, jt + 1);   // async, lands before next barrier

        const unsigned short* sVc = sV + cur * 8192;
        const unsigned short* sKc = sK + cur * 1024;

        // K A-frag for this wave's 32-j half: rows j-local = 32jw + m31
        const s16x8 kf = *(const s16x8*)(sKc + (size_t)(32 * jw + m31) * 16 + 8 * h);

        // scores: S^T (D[j][m]) for the 32-j half
        f32x16 sd;
#pragma unroll
        for (int r = 0; r < 16; ++r) sd[r] = 0.f;
        sd = __builtin_amdgcn_mfma_f32_32x32x16_bf16(kf, qf, sd, 0, 0, 0);

        // softmax numerator: exp2 (scale folded), pack quads to bf16 pairs
        uint2 pk[4];
#pragma unroll
        for (int q = 0; q < 4; ++q) {
            const float e0 = EXP2F(sd[4 * q + 0]);
            const float e1 = EXP2F(sd[4 * q + 1]);
            const float e2 = EXP2F(sd[4 * q + 2]);
            const float e3 = EXP2F(sd[4 * q + 3]);
            la0 += e0; la1 += e1; la2 += e2; la3 += e3;
            pk[q].x = cvtpkbf(e0, e1);
            pk[q].y = cvtpkbf(e2, e3);
        }

        // register-only C->B transform via permlane32_swap (verified in r2 kernel)
        s16x8 pf[2];
#pragma unroll
        for (int s1 = 0; s1 < 2; ++s1) {
            const uint2 rx = plswap32(pk[2 * s1].x, pk[2 * s1 + 1].x);
            const uint2 ry = plswap32(pk[2 * s1].y, pk[2 * s1 + 1].y);
            union { s16x8 v; unsigned u[4]; } A;
            A.u[0] = rx.x; A.u[1] = ry.x; A.u[2] = rx.y; A.u[3] = ry.y;
            pf[s1] = A.v;
        }

        // PV: O^T[c][m] += V^T * P^T. V fragment loaded from LDS per-step so
        // the allocator never has to hold all 8 (r3's O-spill root cause).
        const unsigned short* sVw = sVc + (2 * jw) * 2048 + h * 1024 + m31 * 8;
#pragma unroll
        for (int sl = 0; sl < 2; ++sl)
#pragma unroll
            for (int ct = 0; ct < 4; ++ct) {
                const s16x8 vfr = *(const s16x8*)(sVw + sl * 2048 + ct * 256);
                O[ct] = __builtin_amdgcn_mfma_f32_32x32x16_bf16(vfr, pf[sl], O[ct], 0, 0, 0);
            }

        __syncthreads();   // stage arrived (vmcnt drain) + all waves done with cur
        cur ^= 1;
    }
#undef STAGE

    float l_acc = (la0 + la1) + (la2 + la3);
    l_acc += __shfl_xor(l_acc, 32);   // h-halves hold disjoint j subsets

    // ---- 2-way combine between jw partners (w ^ 1): split output by ct-pair ----
    // jw=0 keeps ct{0,1} (c 0..63); jw=1 keeps ct{2,3} (c 64..127).
    if (lane < 32) lb[w * 32 + m31] = l_acc;
    if (jw == 1) {
#pragma unroll
        for (int ci = 0; ci < 2; ++ci)
#pragma unroll
            for (int r = 0; r < 16; ++r) {
                const int cl = 32 * ci + (r & 3) + 8 * (r >> 2) + 4 * h;
                cO[(mw * 64 + cl) * 33 + m31] = O[ci][r];
            }
    }
    __syncthreads();
    const float l_tot = l_acc + lb[(w ^ 1) * 32 + m31];
    if (jw == 0) {
#pragma unroll
        for (int ci = 0; ci < 2; ++ci)
#pragma unroll
            for (int r = 0; r < 16; ++r) {
                const int cl = 32 * ci + (r & 3) + 8 * (r >> 2) + 4 * h;
                O[ci][r] += cO[(mw * 64 + cl) * 33 + m31];   // read partner's A...
            }
#pragma unroll
        for (int ci = 0; ci < 2; ++ci)
#pragma unroll
            for (int r = 0; r < 16; ++r) {
                const int cl = 32 * ci + (r & 3) + 8 * (r >> 2) + 4 * h;
                cO[(mw * 64 + cl) * 33 + m31] = O[2 + ci][r]; // ...then write own B
            }
    }
    __syncthreads();
    if (jw == 1) {
#pragma unroll
        for (int ci = 0; ci < 2; ++ci)
#pragma unroll
            for (int r = 0; r < 16; ++r) {
                const int cl = 32 * ci + (r & 3) + 8 * (r >> 2) + 4 * h;
                O[2 + ci][r] += cO[(mw * 64 + cl) * 33 + m31];
            }
    }

    // ---- epilogue: each wave stores its kept 64 channels for its 32 rows ----
    const float linv = 1.f / l_tot;
    const float g = gamma[0];
#pragma unroll
    for (int ci = 0; ci < 2; ++ci) {
        const int ct = 2 * jw + ci;
#pragma unroll
        for (int r = 0; r < 16; ++r) {
            const int c = 32 * ct + (r & 3) + 8 * (r >> 2) + 4 * h;
            const size_t idx = ((size_t)b * 128 + c) * NTOK + mrow + m31;
            out[idx] = fmaf(g, O[ct][r] * linv, x[idx]);
        }
    }
}

extern "C" void kernel_launch(void* const* d_in, const int* in_sizes, int n_in,
                              void* d_out, int out_size, void* d_ws, size_t ws_size,
                              hipStream_t stream)
{
    const float* x     = (const float*)d_in[0];
    const float* Wq    = (const float*)d_in[1];
    const float* bq    = (const float*)d_in[2];
    const float* Wk    = (const float*)d_in[3];
    const float* bk    = (const float*)d_in[4];
    const float* Wv    = (const float*)d_in[5];
    const float* bv    = (const float*)d_in[6];
    const float* gamma = (const float*)d_in[7];
    float* out = (float*)d_out;

    // workspace (bf16 elements)
    unsigned short* qb  = (unsigned short*)d_ws;                 // 8*4096*16
    unsigned short* kb  = qb  + (size_t)NB_ * NTOK * 16;
    unsigned short* vt  = kb  + (size_t)NB_ * NTOK * 16;         // 8*128*4096 (fragment-major)
    unsigned short* wvb = vt  + (size_t)NB_ * 128 * NTOK;        // 128*128
    unsigned short* wqb = wvb + 16384;                           // 16*128
    unsigned short* wkb = wqb + 2048;

    wcvt_kernel<<<80, 256, 0, stream>>>(Wq, Wk, Wv, wvb, wqb, wkb);
    proj_kernel<<<512, 256, 0, stream>>>(x, wvb, wqb, wkb, bq, bk, bv, qb, kb, vt);
    flash_kernel<<<256, 512, 0, stream>>>(qb, kb, vt, x, gamma, out);
}

// Round 5
// 371.389 us; speedup vs baseline: 1.0792x; 1.0792x over previous
//
#include <hip/hip_runtime.h>
#include <cstddef>
#include <cstdint>

#define NTOK 4096
#define NB_  8

// 0.25 (=1/sqrt(Cq)) * log2(e): folded into q so flash can use raw exp2.
#define QSCALE 0.36067376022224085f

typedef float f32x4  __attribute__((ext_vector_type(4)));
typedef float f32x16 __attribute__((ext_vector_type(16)));
typedef short s16x8  __attribute__((ext_vector_type(8)));

#if __has_builtin(__builtin_amdgcn_exp2f)
#define EXP2F(x) __builtin_amdgcn_exp2f(x)
#else
#define EXP2F(x) exp2f(x)
#endif

static __device__ __forceinline__ unsigned short f2bf(float f) {
    unsigned u = __float_as_uint(f);
    unsigned r = (u + 0x7FFFu + ((u >> 16) & 1u)) >> 16;
    return (unsigned short)r;
}

// 2 f32 -> packed bf16 pair (low half = a), RNE.
static __device__ __forceinline__ unsigned cvtpkbf(float a, float b) {
    unsigned r;
    asm("v_cvt_pk_bf16_f32 %0, %1, %2" : "=v"(r) : "v"(a), "v"(b));
    return r;
}

// v_permlane32_swap_b32: ret.x = [a(lanes0-31) | b(lanes0-31)],
//                        ret.y = [a(lanes32-63) | b(lanes32-63)].
static __device__ __forceinline__ uint2 plswap32(unsigned a, unsigned b) {
#if __has_builtin(__builtin_amdgcn_permlane32_swap)
    auto r = __builtin_amdgcn_permlane32_swap((int)a, (int)b, false, false);
    return make_uint2((unsigned)r[0], (unsigned)r[1]);
#else
    const int xa = (((int)threadIdx.x & 63) ^ 32) << 2;
    const unsigned pa = (unsigned)__builtin_amdgcn_ds_bpermute(xa, (int)a);
    const unsigned pb = (unsigned)__builtin_amdgcn_ds_bpermute(xa, (int)b);
    const bool hi = (threadIdx.x & 32) != 0;
    return make_uint2(hi ? pb : a, hi ? b : pa);
#endif
}

// async global(16B/lane) -> LDS(base + lane*16), wave-level
static __device__ __forceinline__ void gload16(const void* g, void* l) {
    __builtin_amdgcn_global_load_lds(
        (const __attribute__((address_space(1))) unsigned int*)g,
        (__attribute__((address_space(3))) unsigned int*)l, 16, 0, 0);
}

// ---------------- P0: weights fp32 -> bf16 ----------------
__global__ __launch_bounds__(256) void wcvt_kernel(
    const float* __restrict__ Wq, const float* __restrict__ Wk, const float* __restrict__ Wv,
    unsigned short* __restrict__ wvb, unsigned short* __restrict__ wqb,
    unsigned short* __restrict__ wkb)
{
    int i = blockIdx.x * 256 + threadIdx.x;  // 0..20479
    if (i < 16384)      wvb[i]         = f2bf(Wv[i]);
    else if (i < 18432) wqb[i - 16384] = f2bf(Wq[i - 16384]);
    else                wkb[i - 18432] = f2bf(Wk[i - 18432]);
}

// ---------------- P1: fused transpose + projections ----------------
// Flat grid 512 blocks; b = blk & 7 pins each batch to one XCD so outputs land
// in the L2 flash will read. V is written in flash's fragment-major layout:
// v3[b][jt=j>>6][s=(j>>4)&3][h=(j>>3)&1][c][e=j&7]
// MFMA operand order chosen so each thread's 4 accumulator elements map to
// CONSECUTIVE addresses -> all stores are 8B uint2, wave-coalesced.
__global__ __launch_bounds__(256) void proj_kernel(
    const float* __restrict__ x,
    const unsigned short* __restrict__ wvb, const unsigned short* __restrict__ wqb,
    const unsigned short* __restrict__ wkb,
    const float* __restrict__ bq, const float* __restrict__ bk, const float* __restrict__ bv,
    unsigned short* __restrict__ qb, unsigned short* __restrict__ kb,
    unsigned short* __restrict__ vt)
{
    __shared__ float lt[128][68];   // [c][n0..63], padded rows (16B-aligned stride)
    const int t = threadIdx.x;
    const int w = t >> 6, lane = t & 63;
    const int c16 = lane & 15, g16 = lane >> 4;
    const int b  = blockIdx.x & 7;
    const int n0 = (blockIdx.x >> 3) * 64;

    // stage x tile: 128 rows x 64 floats
    {
        const int n4 = t & 15;
#pragma unroll
        for (int pass = 0; pass < 8; ++pass) {
            const int c = (t >> 4) + 16 * pass;
            const float4 val = ((const float4*)(x + ((size_t)b * 128 + c) * NTOK + n0))[n4];
            *(float4*)&lt[c][n4 * 4] = val;
        }
    }
    __syncthreads();

    // xf fragments for this wave's 16 tokens (token = n0 + 16w + c16)
    // A-frag view: A[m=token(c16)][k=ch 8g16+e]; B-frag view: B[k=ch][n=token(c16)]
    const int nl = 16 * w + c16;
    s16x8 xf[4];
#pragma unroll
    for (int kc = 0; kc < 4; ++kc) {
        unsigned rr[8];
#pragma unroll
        for (int i = 0; i < 8; ++i) {
            const unsigned u = __float_as_uint(lt[32 * kc + 8 * g16 + i][nl]);
            rr[i] = u + 0x7FFFu + ((u >> 16) & 1u);
        }
        union { s16x8 v; unsigned u[4]; } cvt;
#pragma unroll
        for (int d = 0; d < 4; ++d)
            cvt.u[d] = __builtin_amdgcn_perm(rr[2 * d + 1], rr[2 * d], 0x07060302u);
        xf[kc] = cvt.v;
    }

    // ---- V = Wv * X  (fragment-major for flash) ----
    // mfma(xf, wf): D[m=token 4g16+r][n=c_out 16mt+c16].
    // token j = n0 + 16w + 4g16 + r: s=w, h=g16>>1, e=4(g16&1)+r -> r contiguous.
    unsigned short* vwp = vt + (size_t)b * (NTOK * 128) +
                          (size_t)(((n0 >> 6) * 8) + 2 * w + (g16 >> 1)) * 1024 + 4 * (g16 & 1);
#pragma unroll
    for (int mt = 0; mt < 8; ++mt) {
        f32x4 acc = {0.f, 0.f, 0.f, 0.f};
#pragma unroll
        for (int kc = 0; kc < 4; ++kc) {
            const s16x8 wf = *(const s16x8*)(wvb + (size_t)(16 * mt + c16) * 128 + 32 * kc + 8 * g16);
            acc = __builtin_amdgcn_mfma_f32_16x16x32_bf16(xf[kc], wf, acc, 0, 0, 0);
        }
        const float bvv = bv[16 * mt + c16];
        uint2 pkv;
        pkv.x = cvtpkbf(acc[0] + bvv, acc[1] + bvv);
        pkv.y = cvtpkbf(acc[2] + bvv, acc[3] + bvv);
        *(uint2*)(vwp + (size_t)(16 * mt + c16) * 8) = pkv;
    }
    // ---- Q, K ----
    // mfma(wqf, xf): D[m=qch 4g16+r][n=token c16] -> 4 consecutive qch per thread.
    f32x4 aq = {0.f, 0.f, 0.f, 0.f}, ak = {0.f, 0.f, 0.f, 0.f};
#pragma unroll
    for (int kc = 0; kc < 4; ++kc) {
        const s16x8 wqf = *(const s16x8*)(wqb + (size_t)c16 * 128 + 32 * kc + 8 * g16);
        const s16x8 wkf = *(const s16x8*)(wkb + (size_t)c16 * 128 + 32 * kc + 8 * g16);
        aq = __builtin_amdgcn_mfma_f32_16x16x32_bf16(wqf, xf[kc], aq, 0, 0, 0);
        ak = __builtin_amdgcn_mfma_f32_16x16x32_bf16(wkf, xf[kc], ak, 0, 0, 0);
    }
    const float4 bq4 = *(const float4*)(bq + 4 * g16);
    const float4 bk4 = *(const float4*)(bk + 4 * g16);
    const int n = n0 + 16 * w + c16;
    uint2 pq, pkk;
    pq.x  = cvtpkbf(QSCALE * (aq[0] + bq4.x), QSCALE * (aq[1] + bq4.y));
    pq.y  = cvtpkbf(QSCALE * (aq[2] + bq4.z), QSCALE * (aq[3] + bq4.w));
    pkk.x = cvtpkbf(ak[0] + bk4.x, ak[1] + bk4.y);
    pkk.y = cvtpkbf(ak[2] + bk4.z, ak[3] + bk4.w);
    *(uint2*)(qb + ((size_t)b * NTOK + n) * 16 + 4 * g16) = pq;
    *(uint2*)(kb + ((size_t)b * NTOK + n) * 16 + 4 * g16) = pkk;
}

// ---------------- P2: flash attention, LDS-shared K/V tiles ----------------
// Grid 512 blocks (2/CU): b = blk & 7 (XCD-pinned; both co-resident blocks on a
// CU share the batch -> L2-co-traveling tile streams), m-tile = blk>>3 (64 q rows).
// 4 waves = (mw 0..1) x (jw 0..1): wave owns 32 q-rows (mrow = m0+32mw) and the
// jw-th 32-j half of every staged 64-j tile. V/K tiles double-buffered via
// async global_load_lds; all 4 waves share each tile.
//
// r3/r4 lesson: with 512-thr blocks + launch_bounds(512,2) the allocator
// spilled the O accumulator (256B/thread) to scratch every iteration -> 2.2 GB
// HBM writes, 306us write-bound. Source-level "load vf late" did NOT stop the
// scheduler from hoisting the 8 ds_reads back up (r4 binary == r3 binary).
// Fix: the r2-PROVEN register envelope (256 thr, launch_bounds(256,4): 64 arch
// + 64 acc, no spill) + sched_barrier(0) fence so vf reads can't hoist above
// the P-transform (bounded live state ~122 regs even with full hoist).
__global__ __launch_bounds__(256, 4) void flash_kernel(
    const unsigned short* __restrict__ qb, const unsigned short* __restrict__ kb,
    const unsigned short* __restrict__ vt, const float* __restrict__ x,
    const float* __restrict__ gamma, float* __restrict__ out)
{
    __shared__ __align__(16) unsigned char smem[37888];
    unsigned short* sV = (unsigned short*)smem;              // [2][8192] (16KB each)
    unsigned short* sK = (unsigned short*)(smem + 32768);    // [2][1024] (2KB each)
    float* lb = (float*)(smem + 36864);                      // [4][32]
    float* cO = (float*)smem;                                // combine alias [2*64][33]

    const int t = threadIdx.x;
    const int w = t >> 6, lane = t & 63;
    const int m31 = lane & 31, h = lane >> 5;
    const int mw = w >> 1, jw = w & 1;
    const int b  = blockIdx.x & 7;
    const int m0 = (blockIdx.x >> 3) * 64;
    const int mrow = m0 + 32 * mw;

    const unsigned short* vtile0 = vt + (size_t)b * (NTOK * 128);  // 16KB per jt tile, contiguous
    const unsigned short* ktile0 = kb + (size_t)b * (NTOK * 16);   // 2KB per jt tile, contiguous

    // Q B-frag: B[k=ch 8h+e][n=m31]; scale (incl. log2e) pre-folded into qb.
    const s16x8 qf = *(const s16x8*)(qb + ((size_t)b * NTOK + mrow + m31) * 16 + 8 * h);

    f32x16 O[4];
#pragma unroll
    for (int ct = 0; ct < 4; ++ct)
#pragma unroll
        for (int r = 0; r < 16; ++r) O[ct][r] = 0.f;
    float la0 = 0.f, la1 = 0.f, la2 = 0.f, la3 = 0.f;

    // stage tile jt_ into buffer d: V 16KB (4 calls/wave, 4KB each), K 2KB (waves 0,1)
#define STAGE(d, jt_) do {                                                          \
        const unsigned short* vs_ = vtile0 + (size_t)(jt_) * 8192 + w * 2048 + lane * 8; \
        gload16(vs_,        smem + (d) * 16384 + w * 4096);                         \
        gload16(vs_ + 512,  smem + (d) * 16384 + w * 4096 + 1024);                  \
        gload16(vs_ + 1024, smem + (d) * 16384 + w * 4096 + 2048);                  \
        gload16(vs_ + 1536, smem + (d) * 16384 + w * 4096 + 3072);                  \
        if (w < 2) {                                                                \
            const unsigned short* ks_ = ktile0 + (size_t)(jt_) * 1024 + w * 512 + lane * 8; \
            gload16(ks_, smem + 32768 + (d) * 2048 + w * 1024);                     \
        }                                                                           \
    } while (0)

    STAGE(0, 0);
    __syncthreads();   // drains vmcnt -> tile 0 resident

    int cur = 0;
    for (int jt = 0; jt < 64; ++jt) {
        if (jt < 63) STAGE(cur ^ 1, jt + 1);   // async, drains at loop-end barrier

        const unsigned short* sVc = sV + cur * 8192;
        const unsigned short* sKc = sK + cur * 1024;

        // K A-frag for this wave's 32-j half: rows j-local = 32jw + m31
        const s16x8 kf = *(const s16x8*)(sKc + (size_t)(32 * jw + m31) * 16 + 8 * h);

        // scores: S^T (D[j][m]) for the 32-j half
        f32x16 sd;
#pragma unroll
        for (int r = 0; r < 16; ++r) sd[r] = 0.f;
        sd = __builtin_amdgcn_mfma_f32_32x32x16_bf16(kf, qf, sd, 0, 0, 0);

        // softmax numerator: exp2 (scale folded), pack quads to bf16 pairs
        uint2 pk[4];
#pragma unroll
        for (int q = 0; q < 4; ++q) {
            const float e0 = EXP2F(sd[4 * q + 0]);
            const float e1 = EXP2F(sd[4 * q + 1]);
            const float e2 = EXP2F(sd[4 * q + 2]);
            const float e3 = EXP2F(sd[4 * q + 3]);
            la0 += e0; la1 += e1; la2 += e2; la3 += e3;
            pk[q].x = cvtpkbf(e0, e1);
            pk[q].y = cvtpkbf(e2, e3);
        }

        // register-only C->B transform via permlane32_swap (r2-verified)
        s16x8 pf[2];
#pragma unroll
        for (int s1 = 0; s1 < 2; ++s1) {
            const uint2 rx = plswap32(pk[2 * s1].x, pk[2 * s1 + 1].x);
            const uint2 ry = plswap32(pk[2 * s1].y, pk[2 * s1 + 1].y);
            union { s16x8 v; unsigned u[4]; } A;
            A.u[0] = rx.x; A.u[1] = ry.x; A.u[2] = rx.y; A.u[3] = ry.y;
            pf[s1] = A.v;
        }

        // fence: vf ds_reads below cannot hoist above this point, so their live
        // range starts after pk is dead (bounds peak pressure inside the proven
        // 128-reg envelope even if the scheduler hoists all 8 reads here).
        __builtin_amdgcn_sched_barrier(0);

        // PV: O^T[c][m] += V^T * P^T
        const unsigned short* sVw = sVc + (2 * jw) * 2048 + h * 1024 + m31 * 8;
#pragma unroll
        for (int sl = 0; sl < 2; ++sl)
#pragma unroll
            for (int ct = 0; ct < 4; ++ct) {
                const s16x8 vfr = *(const s16x8*)(sVw + sl * 2048 + ct * 256);
                O[ct] = __builtin_amdgcn_mfma_f32_32x32x16_bf16(vfr, pf[sl], O[ct], 0, 0, 0);
            }

        __syncthreads();   // stage arrived (vmcnt drain) + all waves done with cur
        cur ^= 1;
    }
#undef STAGE

    float l_acc = (la0 + la1) + (la2 + la3);
    l_acc += __shfl_xor(l_acc, 32);   // h-halves hold disjoint j subsets

    // ---- 2-way combine between jw partners (w ^ 1): split output by ct-pair ----
    // jw=0 keeps ct{0,1} (c 0..63); jw=1 keeps ct{2,3} (c 64..127).
    if (lane < 32) lb[w * 32 + m31] = l_acc;
    if (jw == 1) {
#pragma unroll
        for (int ci = 0; ci < 2; ++ci)
#pragma unroll
            for (int r = 0; r < 16; ++r) {
                const int cl = 32 * ci + (r & 3) + 8 * (r >> 2) + 4 * h;
                cO[(mw * 64 + cl) * 33 + m31] = O[ci][r];
            }
    }
    __syncthreads();
    const float l_tot = l_acc + lb[(w ^ 1) * 32 + m31];
    if (jw == 0) {
#pragma unroll
        for (int ci = 0; ci < 2; ++ci)
#pragma unroll
            for (int r = 0; r < 16; ++r) {
                const int cl = 32 * ci + (r & 3) + 8 * (r >> 2) + 4 * h;
                O[ci][r] += cO[(mw * 64 + cl) * 33 + m31];   // read partner's A...
            }
#pragma unroll
        for (int ci = 0; ci < 2; ++ci)
#pragma unroll
            for (int r = 0; r < 16; ++r) {
                const int cl = 32 * ci + (r & 3) + 8 * (r >> 2) + 4 * h;
                cO[(mw * 64 + cl) * 33 + m31] = O[2 + ci][r]; // ...then write own B
            }
    }
    __syncthreads();
    if (jw == 1) {
#pragma unroll
        for (int ci = 0; ci < 2; ++ci)
#pragma unroll
            for (int r = 0; r < 16; ++r) {
                const int cl = 32 * ci + (r & 3) + 8 * (r >> 2) + 4 * h;
                O[2 + ci][r] += cO[(mw * 64 + cl) * 33 + m31];
            }
    }

    // ---- epilogue: each wave stores its kept 64 channels for its 32 rows ----
    const float linv = 1.f / l_tot;
    const float g = gamma[0];
#pragma unroll
    for (int ci = 0; ci < 2; ++ci) {
        const int ct = 2 * jw + ci;
#pragma unroll
        for (int r = 0; r < 16; ++r) {
            const int c = 32 * ct + (r & 3) + 8 * (r >> 2) + 4 * h;
            const size_t idx = ((size_t)b * 128 + c) * NTOK + mrow + m31;
            out[idx] = fmaf(g, O[ct][r] * linv, x[idx]);
        }
    }
}

extern "C" void kernel_launch(void* const* d_in, const int* in_sizes, int n_in,
                              void* d_out, int out_size, void* d_ws, size_t ws_size,
                              hipStream_t stream)
{
    const float* x     = (const float*)d_in[0];
    const float* Wq    = (const float*)d_in[1];
    const float* bq    = (const float*)d_in[2];
    const float* Wk    = (const float*)d_in[3];
    const float* bk    = (const float*)d_in[4];
    const float* Wv    = (const float*)d_in[5];
    const float* bv    = (const float*)d_in[6];
    const float* gamma = (const float*)d_in[7];
    float* out = (float*)d_out;

    // workspace (bf16 elements)
    unsigned short* qb  = (unsigned short*)d_ws;                 // 8*4096*16
    unsigned short* kb  = qb  + (size_t)NB_ * NTOK * 16;
    unsigned short* vt  = kb  + (size_t)NB_ * NTOK * 16;         // 8*128*4096 (fragment-major)
    unsigned short* wvb = vt  + (size_t)NB_ * 128 * NTOK;        // 128*128
    unsigned short* wqb = wvb + 16384;                           // 16*128
    unsigned short* wkb = wqb + 2048;

    wcvt_kernel<<<80, 256, 0, stream>>>(Wq, Wk, Wv, wvb, wqb, wkb);
    proj_kernel<<<512, 256, 0, stream>>>(x, wvb, wqb, wkb, bq, bk, bv, qb, kb, vt);
    flash_kernel<<<512, 256, 0, stream>>>(qb, kb, vt, x, gamma, out);
}

// Round 6
// 156.442 us; speedup vs baseline: 2.5619x; 2.3740x over previous
//
#include <hip/hip_runtime.h>
#include <cstddef>
#include <cstdint>

#define NTOK 4096
#define NB_  8

// 0.25 (=1/sqrt(Cq)) * log2(e): folded into q so flash can use raw exp2.
#define QSCALE 0.36067376022224085f

typedef float f32x4  __attribute__((ext_vector_type(4)));
typedef float f32x16 __attribute__((ext_vector_type(16)));
typedef short s16x8  __attribute__((ext_vector_type(8)));

#if __has_builtin(__builtin_amdgcn_exp2f)
#define EXP2F(x) __builtin_amdgcn_exp2f(x)
#else
#define EXP2F(x) exp2f(x)
#endif

static __device__ __forceinline__ unsigned short f2bf(float f) {
    unsigned u = __float_as_uint(f);
    unsigned r = (u + 0x7FFFu + ((u >> 16) & 1u)) >> 16;
    return (unsigned short)r;
}

// 2 f32 -> packed bf16 pair (low half = a), RNE.
static __device__ __forceinline__ unsigned cvtpkbf(float a, float b) {
    unsigned r;
    asm("v_cvt_pk_bf16_f32 %0, %1, %2" : "=v"(r) : "v"(a), "v"(b));
    return r;
}

// v_permlane32_swap_b32: ret.x = [a(lanes0-31) | b(lanes0-31)],
//                        ret.y = [a(lanes32-63) | b(lanes32-63)].
static __device__ __forceinline__ uint2 plswap32(unsigned a, unsigned b) {
#if __has_builtin(__builtin_amdgcn_permlane32_swap)
    auto r = __builtin_amdgcn_permlane32_swap((int)a, (int)b, false, false);
    return make_uint2((unsigned)r[0], (unsigned)r[1]);
#else
    const int xa = (((int)threadIdx.x & 63) ^ 32) << 2;
    const unsigned pa = (unsigned)__builtin_amdgcn_ds_bpermute(xa, (int)a);
    const unsigned pb = (unsigned)__builtin_amdgcn_ds_bpermute(xa, (int)b);
    const bool hi = (threadIdx.x & 32) != 0;
    return make_uint2(hi ? pb : a, hi ? b : pa);
#endif
}

// async global(16B/lane) -> LDS(base + lane*16), wave-level
static __device__ __forceinline__ void gload16(const void* g, void* l) {
    __builtin_amdgcn_global_load_lds(
        (const __attribute__((address_space(1))) unsigned int*)g,
        (__attribute__((address_space(3))) unsigned int*)l, 16, 0, 0);
}

// ---------------- P0: weights fp32 -> bf16 ----------------
__global__ __launch_bounds__(256) void wcvt_kernel(
    const float* __restrict__ Wq, const float* __restrict__ Wk, const float* __restrict__ Wv,
    unsigned short* __restrict__ wvb, unsigned short* __restrict__ wqb,
    unsigned short* __restrict__ wkb)
{
    int i = blockIdx.x * 256 + threadIdx.x;  // 0..20479
    if (i < 16384)      wvb[i]         = f2bf(Wv[i]);
    else if (i < 18432) wqb[i - 16384] = f2bf(Wq[i - 16384]);
    else                wkb[i - 18432] = f2bf(Wk[i - 18432]);
}

// ---------------- P1: fused transpose + projections ----------------
// Flat grid 512 blocks; b = blk & 7 pins each batch to one XCD so outputs land
// in the L2 flash will read. V is written in flash's fragment-major layout:
// v3[b][jt=j>>6][s=(j>>4)&3][h=(j>>3)&1][c][e=j&7]
// MFMA operand order chosen so each thread's 4 accumulator elements map to
// CONSECUTIVE addresses -> all stores are 8B uint2, wave-coalesced.
__global__ __launch_bounds__(256) void proj_kernel(
    const float* __restrict__ x,
    const unsigned short* __restrict__ wvb, const unsigned short* __restrict__ wqb,
    const unsigned short* __restrict__ wkb,
    const float* __restrict__ bq, const float* __restrict__ bk, const float* __restrict__ bv,
    unsigned short* __restrict__ qb, unsigned short* __restrict__ kb,
    unsigned short* __restrict__ vt)
{
    __shared__ float lt[128][68];   // [c][n0..63], padded rows (16B-aligned stride)
    const int t = threadIdx.x;
    const int w = t >> 6, lane = t & 63;
    const int c16 = lane & 15, g16 = lane >> 4;
    const int b  = blockIdx.x & 7;
    const int n0 = (blockIdx.x >> 3) * 64;

    // stage x tile: 128 rows x 64 floats
    {
        const int n4 = t & 15;
#pragma unroll
        for (int pass = 0; pass < 8; ++pass) {
            const int c = (t >> 4) + 16 * pass;
            const float4 val = ((const float4*)(x + ((size_t)b * 128 + c) * NTOK + n0))[n4];
            *(float4*)&lt[c][n4 * 4] = val;
        }
    }
    __syncthreads();

    // xf fragments for this wave's 16 tokens (token = n0 + 16w + c16)
    // A-frag view: A[m=token(c16)][k=ch 8g16+e]; B-frag view: B[k=ch][n=token(c16)]
    const int nl = 16 * w + c16;
    s16x8 xf[4];
#pragma unroll
    for (int kc = 0; kc < 4; ++kc) {
        unsigned rr[8];
#pragma unroll
        for (int i = 0; i < 8; ++i) {
            const unsigned u = __float_as_uint(lt[32 * kc + 8 * g16 + i][nl]);
            rr[i] = u + 0x7FFFu + ((u >> 16) & 1u);
        }
        union { s16x8 v; unsigned u[4]; } cvt;
#pragma unroll
        for (int d = 0; d < 4; ++d)
            cvt.u[d] = __builtin_amdgcn_perm(rr[2 * d + 1], rr[2 * d], 0x07060302u);
        xf[kc] = cvt.v;
    }

    // ---- V = Wv * X  (fragment-major for flash) ----
    // mfma(xf, wf): D[m=token 4g16+r][n=c_out 16mt+c16].
    // token j = n0 + 16w + 4g16 + r: s=w, h=g16>>1, e=4(g16&1)+r -> r contiguous.
    unsigned short* vwp = vt + (size_t)b * (NTOK * 128) +
                          (size_t)(((n0 >> 6) * 8) + 2 * w + (g16 >> 1)) * 1024 + 4 * (g16 & 1);
#pragma unroll
    for (int mt = 0; mt < 8; ++mt) {
        f32x4 acc = {0.f, 0.f, 0.f, 0.f};
#pragma unroll
        for (int kc = 0; kc < 4; ++kc) {
            const s16x8 wf = *(const s16x8*)(wvb + (size_t)(16 * mt + c16) * 128 + 32 * kc + 8 * g16);
            acc = __builtin_amdgcn_mfma_f32_16x16x32_bf16(xf[kc], wf, acc, 0, 0, 0);
        }
        const float bvv = bv[16 * mt + c16];
        uint2 pkv;
        pkv.x = cvtpkbf(acc[0] + bvv, acc[1] + bvv);
        pkv.y = cvtpkbf(acc[2] + bvv, acc[3] + bvv);
        *(uint2*)(vwp + (size_t)(16 * mt + c16) * 8) = pkv;
    }
    // ---- Q, K ----
    // mfma(wqf, xf): D[m=qch 4g16+r][n=token c16] -> 4 consecutive qch per thread.
    f32x4 aq = {0.f, 0.f, 0.f, 0.f}, ak = {0.f, 0.f, 0.f, 0.f};
#pragma unroll
    for (int kc = 0; kc < 4; ++kc) {
        const s16x8 wqf = *(const s16x8*)(wqb + (size_t)c16 * 128 + 32 * kc + 8 * g16);
        const s16x8 wkf = *(const s16x8*)(wkb + (size_t)c16 * 128 + 32 * kc + 8 * g16);
        aq = __builtin_amdgcn_mfma_f32_16x16x32_bf16(wqf, xf[kc], aq, 0, 0, 0);
        ak = __builtin_amdgcn_mfma_f32_16x16x32_bf16(wkf, xf[kc], ak, 0, 0, 0);
    }
    const float4 bq4 = *(const float4*)(bq + 4 * g16);
    const float4 bk4 = *(const float4*)(bk + 4 * g16);
    const int n = n0 + 16 * w + c16;
    uint2 pq, pkk;
    pq.x  = cvtpkbf(QSCALE * (aq[0] + bq4.x), QSCALE * (aq[1] + bq4.y));
    pq.y  = cvtpkbf(QSCALE * (aq[2] + bq4.z), QSCALE * (aq[3] + bq4.w));
    pkk.x = cvtpkbf(ak[0] + bk4.x, ak[1] + bk4.y);
    pkk.y = cvtpkbf(ak[2] + bk4.z, ak[3] + bk4.w);
    *(uint2*)(qb + ((size_t)b * NTOK + n) * 16 + 4 * g16) = pq;
    *(uint2*)(kb + ((size_t)b * NTOK + n) * 16 + 4 * g16) = pkk;
}

// ---------------- P2: flash attention, LDS-shared K/V, channel-split waves ----
// Grid 512 blocks (2/CU): b = blk & 7 (XCD-pinned batch), m-tile = blk>>3 (64 q rows).
// 4 waves = (mw 0..1) x (cv 0..1): wave owns 32 q-rows (mrow = m0+32mw) and 64
// OUTPUT CHANNELS (ct in {2cv, 2cv+1}); it processes BOTH 32-j halves of every
// staged tile (QK MFMA duplicated across cv partners - 2 of 10 MFMAs/tile).
//
// Why channel-split (r3-r5 lesson): j-split waves need O[4] = 64 loop-carried
// acc regs; with transients that demand exceeds the 128-reg/4-wave cap and the
// allocator spills O to scratch every iteration (2.2 GB -> 1.6 GB HBM writes,
// ~300us write-bound across three attempts). Channel-split halves O to 32,
// removes the entire 4-way LDS combine (each wave's l_acc covers all j), and
// with launch_bounds(256,2) (grid gives only 2 blocks/CU anyway) spill is
// structurally impossible. Inner math per t2-half is r2's verified code.
__global__ __launch_bounds__(256, 2) void flash_kernel(
    const unsigned short* __restrict__ qb, const unsigned short* __restrict__ kb,
    const unsigned short* __restrict__ vt, const float* __restrict__ x,
    const float* __restrict__ gamma, float* __restrict__ out)
{
    __shared__ __align__(16) unsigned char smem[36864];
    unsigned short* sV = (unsigned short*)smem;              // [2][8192] (16KB each)
    unsigned short* sK = (unsigned short*)(smem + 32768);    // [2][1024] (2KB each)

    const int t = threadIdx.x;
    const int w = t >> 6, lane = t & 63;
    const int m31 = lane & 31, h = lane >> 5;
    const int mw = w >> 1, cv = w & 1;
    const int b  = blockIdx.x & 7;
    const int m0 = (blockIdx.x >> 3) * 64;
    const int mrow = m0 + 32 * mw;

    const unsigned short* vtile0 = vt + (size_t)b * (NTOK * 128);  // 16KB per jt tile, contiguous
    const unsigned short* ktile0 = kb + (size_t)b * (NTOK * 16);   // 2KB per jt tile, contiguous

    // Q B-frag: B[k=ch 8h+e][n=m31]; scale (incl. log2e) pre-folded into qb.
    const s16x8 qf = *(const s16x8*)(qb + ((size_t)b * NTOK + mrow + m31) * 16 + 8 * h);

    f32x16 O[2];   // 32 loop-carried acc regs (ct = 2cv + ci)
#pragma unroll
    for (int ci = 0; ci < 2; ++ci)
#pragma unroll
        for (int r = 0; r < 16; ++r) O[ci][r] = 0.f;
    float la0 = 0.f, la1 = 0.f, la2 = 0.f, la3 = 0.f;

    // stage tile jt_ into buffer d: V 16KB (4 calls/wave, 4KB each), K 2KB (waves 0,1)
#define STAGE(d, jt_) do {                                                          \
        const unsigned short* vs_ = vtile0 + (size_t)(jt_) * 8192 + w * 2048 + lane * 8; \
        gload16(vs_,        smem + (d) * 16384 + w * 4096);                         \
        gload16(vs_ + 512,  smem + (d) * 16384 + w * 4096 + 1024);                  \
        gload16(vs_ + 1024, smem + (d) * 16384 + w * 4096 + 2048);                  \
        gload16(vs_ + 1536, smem + (d) * 16384 + w * 4096 + 3072);                  \
        if (w < 2) {                                                                \
            const unsigned short* ks_ = ktile0 + (size_t)(jt_) * 1024 + w * 512 + lane * 8; \
            gload16(ks_, smem + 32768 + (d) * 2048 + w * 1024);                     \
        }                                                                           \
    } while (0)

    STAGE(0, 0);
    __syncthreads();   // drains vmcnt -> tile 0 resident

    int cur = 0;
    for (int jt = 0; jt < 64; ++jt) {
        if (jt < 63) STAGE(cur ^ 1, jt + 1);   // async, drains at loop-end barrier

        const unsigned short* sVc = sV + cur * 8192;
        const unsigned short* sKc = sK + cur * 1024;

        // K A-frags for both 32-j halves of this tile
        const s16x8 kf0 = *(const s16x8*)(sKc + (size_t)m31 * 16 + 8 * h);
        const s16x8 kf1 = *(const s16x8*)(sKc + (size_t)(32 + m31) * 16 + 8 * h);

#pragma unroll
        for (int t2 = 0; t2 < 2; ++t2) {
            // scores: S^T (D[j][m]) for this 32-j half
            f32x16 sd;
#pragma unroll
            for (int r = 0; r < 16; ++r) sd[r] = 0.f;
            sd = __builtin_amdgcn_mfma_f32_32x32x16_bf16(t2 ? kf1 : kf0, qf, sd, 0, 0, 0);

            // softmax numerator: exp2 (scale folded), pack quads to bf16 pairs
            uint2 pk[4];
#pragma unroll
            for (int q = 0; q < 4; ++q) {
                const float e0 = EXP2F(sd[4 * q + 0]);
                const float e1 = EXP2F(sd[4 * q + 1]);
                const float e2 = EXP2F(sd[4 * q + 2]);
                const float e3 = EXP2F(sd[4 * q + 3]);
                la0 += e0; la1 += e1; la2 += e2; la3 += e3;
                pk[q].x = cvtpkbf(e0, e1);
                pk[q].y = cvtpkbf(e2, e3);
            }

            // register-only C->B transform via permlane32_swap (r2-verified)
            s16x8 pf[2];
#pragma unroll
            for (int s1 = 0; s1 < 2; ++s1) {
                const uint2 rx = plswap32(pk[2 * s1].x, pk[2 * s1 + 1].x);
                const uint2 ry = plswap32(pk[2 * s1].y, pk[2 * s1 + 1].y);
                union { s16x8 v; unsigned u[4]; } A;
                A.u[0] = rx.x; A.u[1] = ry.x; A.u[2] = rx.y; A.u[3] = ry.y;
                pf[s1] = A.v;
            }

            // PV: O^T[c][m] += V^T * P^T for this half, this wave's 2 ct slices
#pragma unroll
            for (int sl = 0; sl < 2; ++sl)
#pragma unroll
                for (int ci = 0; ci < 2; ++ci) {
                    const s16x8 vfr = *(const s16x8*)(sVc + (2 * t2 + sl) * 2048 + h * 1024 +
                                                      (2 * cv + ci) * 256 + m31 * 8);
                    O[ci] = __builtin_amdgcn_mfma_f32_32x32x16_bf16(vfr, pf[sl], O[ci], 0, 0, 0);
                }
        }

        __syncthreads();   // stage arrived (vmcnt drain) + all waves done with cur
        cur ^= 1;
    }
#undef STAGE

    // full j coverage per wave -> l complete after h-partner exchange; no combine.
    float l_acc = (la0 + la1) + (la2 + la3);
    l_acc += __shfl_xor(l_acc, 32);   // h-halves hold disjoint j subsets

    const float linv = 1.f / l_acc;
    const float g = gamma[0];
#pragma unroll
    for (int ci = 0; ci < 2; ++ci) {
        const int ct = 2 * cv + ci;
#pragma unroll
        for (int r = 0; r < 16; ++r) {
            const int c = 32 * ct + (r & 3) + 8 * (r >> 2) + 4 * h;
            const size_t idx = ((size_t)b * 128 + c) * NTOK + mrow + m31;
            out[idx] = fmaf(g, O[ci][r] * linv, x[idx]);
        }
    }
}

extern "C" void kernel_launch(void* const* d_in, const int* in_sizes, int n_in,
                              void* d_out, int out_size, void* d_ws, size_t ws_size,
                              hipStream_t stream)
{
    const float* x     = (const float*)d_in[0];
    const float* Wq    = (const float*)d_in[1];
    const float* bq    = (const float*)d_in[2];
    const float* Wk    = (const float*)d_in[3];
    const float* bk    = (const float*)d_in[4];
    const float* Wv    = (const float*)d_in[5];
    const float* bv    = (const float*)d_in[6];
    const float* gamma = (const float*)d_in[7];
    float* out = (float*)d_out;

    // workspace (bf16 elements)
    unsigned short* qb  = (unsigned short*)d_ws;                 // 8*4096*16
    unsigned short* kb  = qb  + (size_t)NB_ * NTOK * 16;
    unsigned short* vt  = kb  + (size_t)NB_ * NTOK * 16;         // 8*128*4096 (fragment-major)
    unsigned short* wvb = vt  + (size_t)NB_ * 128 * NTOK;        // 128*128
    unsigned short* wqb = wvb + 16384;                           // 16*128
    unsigned short* wkb = wqb + 2048;

    wcvt_kernel<<<80, 256, 0, stream>>>(Wq, Wk, Wv, wvb, wqb, wkb);
    proj_kernel<<<512, 256, 0, stream>>>(x, wvb, wqb, wkb, bq, bk, bv, qb, kb, vt);
    flash_kernel<<<512, 256, 0, stream>>>(qb, kb, vt, x, gamma, out);
}

// Round 7
// 151.927 us; speedup vs baseline: 2.6380x; 1.0297x over previous
//
#include <hip/hip_runtime.h>
#include <cstddef>
#include <cstdint>

#define NTOK 4096
#define NB_  8

// 0.25 (=1/sqrt(Cq)) * log2(e): folded into q so flash can use raw exp2.
#define QSCALE 0.36067376022224085f

typedef float f32x4  __attribute__((ext_vector_type(4)));
typedef float f32x16 __attribute__((ext_vector_type(16)));
typedef short s16x8  __attribute__((ext_vector_type(8)));

#if __has_builtin(__builtin_amdgcn_exp2f)
#define EXP2F(x) __builtin_amdgcn_exp2f(x)
#else
#define EXP2F(x) exp2f(x)
#endif

static __device__ __forceinline__ unsigned short f2bf(float f) {
    unsigned u = __float_as_uint(f);
    unsigned r = (u + 0x7FFFu + ((u >> 16) & 1u)) >> 16;
    return (unsigned short)r;
}

// 2 f32 -> packed bf16 pair (low half = a), RNE.
static __device__ __forceinline__ unsigned cvtpkbf(float a, float b) {
    unsigned r;
    asm("v_cvt_pk_bf16_f32 %0, %1, %2" : "=v"(r) : "v"(a), "v"(b));
    return r;
}

// v_permlane32_swap_b32: ret.x = [a(lanes0-31) | b(lanes0-31)],
//                        ret.y = [a(lanes32-63) | b(lanes32-63)].
static __device__ __forceinline__ uint2 plswap32(unsigned a, unsigned b) {
#if __has_builtin(__builtin_amdgcn_permlane32_swap)
    auto r = __builtin_amdgcn_permlane32_swap((int)a, (int)b, false, false);
    return make_uint2((unsigned)r[0], (unsigned)r[1]);
#else
    const int xa = (((int)threadIdx.x & 63) ^ 32) << 2;
    const unsigned pa = (unsigned)__builtin_amdgcn_ds_bpermute(xa, (int)a);
    const unsigned pb = (unsigned)__builtin_amdgcn_ds_bpermute(xa, (int)b);
    const bool hi = (threadIdx.x & 32) != 0;
    return make_uint2(hi ? pb : a, hi ? b : pa);
#endif
}

// async global(16B/lane) -> LDS(base + lane*16), wave-level
static __device__ __forceinline__ void gload16(const void* g, void* l) {
    __builtin_amdgcn_global_load_lds(
        (const __attribute__((address_space(1))) unsigned int*)g,
        (__attribute__((address_space(3))) unsigned int*)l, 16, 0, 0);
}

// ---------------- P0: weights fp32 -> bf16 ----------------
__global__ __launch_bounds__(256) void wcvt_kernel(
    const float* __restrict__ Wq, const float* __restrict__ Wk, const float* __restrict__ Wv,
    unsigned short* __restrict__ wvb, unsigned short* __restrict__ wqb,
    unsigned short* __restrict__ wkb)
{
    int i = blockIdx.x * 256 + threadIdx.x;  // 0..20479
    if (i < 16384)      wvb[i]         = f2bf(Wv[i]);
    else if (i < 18432) wqb[i - 16384] = f2bf(Wq[i - 16384]);
    else                wkb[i - 18432] = f2bf(Wk[i - 18432]);
}

// ---------------- P1: fused transpose + projections ----------------
// Flat grid 512 blocks; b = blk & 7 pins each batch to one XCD so outputs land
// in the L2 flash will read. V is written in flash's fragment-major layout:
// v3[b][jt=j>>6][s=(j>>4)&3][h=(j>>3)&1][c][e=j&7]
// MFMA operand order chosen so each thread's 4 accumulator elements map to
// CONSECUTIVE addresses -> all stores are 8B uint2, wave-coalesced.
__global__ __launch_bounds__(256) void proj_kernel(
    const float* __restrict__ x,
    const unsigned short* __restrict__ wvb, const unsigned short* __restrict__ wqb,
    const unsigned short* __restrict__ wkb,
    const float* __restrict__ bq, const float* __restrict__ bk, const float* __restrict__ bv,
    unsigned short* __restrict__ qb, unsigned short* __restrict__ kb,
    unsigned short* __restrict__ vt)
{
    __shared__ float lt[128][68];   // [c][n0..63], padded rows (16B-aligned stride)
    const int t = threadIdx.x;
    const int w = t >> 6, lane = t & 63;
    const int c16 = lane & 15, g16 = lane >> 4;
    const int b  = blockIdx.x & 7;
    const int n0 = (blockIdx.x >> 3) * 64;

    // stage x tile: 128 rows x 64 floats
    {
        const int n4 = t & 15;
#pragma unroll
        for (int pass = 0; pass < 8; ++pass) {
            const int c = (t >> 4) + 16 * pass;
            const float4 val = ((const float4*)(x + ((size_t)b * 128 + c) * NTOK + n0))[n4];
            *(float4*)&lt[c][n4 * 4] = val;
        }
    }
    __syncthreads();

    // xf fragments for this wave's 16 tokens (token = n0 + 16w + c16)
    // A-frag view: A[m=token(c16)][k=ch 8g16+e]; B-frag view: B[k=ch][n=token(c16)]
    const int nl = 16 * w + c16;
    s16x8 xf[4];
#pragma unroll
    for (int kc = 0; kc < 4; ++kc) {
        unsigned rr[8];
#pragma unroll
        for (int i = 0; i < 8; ++i) {
            const unsigned u = __float_as_uint(lt[32 * kc + 8 * g16 + i][nl]);
            rr[i] = u + 0x7FFFu + ((u >> 16) & 1u);
        }
        union { s16x8 v; unsigned u[4]; } cvt;
#pragma unroll
        for (int d = 0; d < 4; ++d)
            cvt.u[d] = __builtin_amdgcn_perm(rr[2 * d + 1], rr[2 * d], 0x07060302u);
        xf[kc] = cvt.v;
    }

    // ---- V = Wv * X  (fragment-major for flash) ----
    // mfma(xf, wf): D[m=token 4g16+r][n=c_out 16mt+c16].
    // token j = n0 + 16w + 4g16 + r: s=w, h=g16>>1, e=4(g16&1)+r -> r contiguous.
    unsigned short* vwp = vt + (size_t)b * (NTOK * 128) +
                          (size_t)(((n0 >> 6) * 8) + 2 * w + (g16 >> 1)) * 1024 + 4 * (g16 & 1);
#pragma unroll
    for (int mt = 0; mt < 8; ++mt) {
        f32x4 acc = {0.f, 0.f, 0.f, 0.f};
#pragma unroll
        for (int kc = 0; kc < 4; ++kc) {
            const s16x8 wf = *(const s16x8*)(wvb + (size_t)(16 * mt + c16) * 128 + 32 * kc + 8 * g16);
            acc = __builtin_amdgcn_mfma_f32_16x16x32_bf16(xf[kc], wf, acc, 0, 0, 0);
        }
        const float bvv = bv[16 * mt + c16];
        uint2 pkv;
        pkv.x = cvtpkbf(acc[0] + bvv, acc[1] + bvv);
        pkv.y = cvtpkbf(acc[2] + bvv, acc[3] + bvv);
        *(uint2*)(vwp + (size_t)(16 * mt + c16) * 8) = pkv;
    }
    // ---- Q, K ----
    // mfma(wqf, xf): D[m=qch 4g16+r][n=token c16] -> 4 consecutive qch per thread.
    f32x4 aq = {0.f, 0.f, 0.f, 0.f}, ak = {0.f, 0.f, 0.f, 0.f};
#pragma unroll
    for (int kc = 0; kc < 4; ++kc) {
        const s16x8 wqf = *(const s16x8*)(wqb + (size_t)c16 * 128 + 32 * kc + 8 * g16);
        const s16x8 wkf = *(const s16x8*)(wkb + (size_t)c16 * 128 + 32 * kc + 8 * g16);
        aq = __builtin_amdgcn_mfma_f32_16x16x32_bf16(wqf, xf[kc], aq, 0, 0, 0);
        ak = __builtin_amdgcn_mfma_f32_16x16x32_bf16(wkf, xf[kc], ak, 0, 0, 0);
    }
    const float4 bq4 = *(const float4*)(bq + 4 * g16);
    const float4 bk4 = *(const float4*)(bk + 4 * g16);
    const int n = n0 + 16 * w + c16;
    uint2 pq, pkk;
    pq.x  = cvtpkbf(QSCALE * (aq[0] + bq4.x), QSCALE * (aq[1] + bq4.y));
    pq.y  = cvtpkbf(QSCALE * (aq[2] + bq4.z), QSCALE * (aq[3] + bq4.w));
    pkk.x = cvtpkbf(ak[0] + bk4.x, ak[1] + bk4.y);
    pkk.y = cvtpkbf(ak[2] + bk4.z, ak[3] + bk4.w);
    *(uint2*)(qb + ((size_t)b * NTOK + n) * 16 + 4 * g16) = pq;
    *(uint2*)(kb + ((size_t)b * NTOK + n) * 16 + 4 * g16) = pkk;
}

// ---------------- P2: flash attention, LDS K/V, channel-split + pf-exchange ----
// Grid 512 blocks (2/CU): b = blk & 7 (XCD-pinned batch), m-tile = blk>>3 (64 q rows).
// 4 waves = (mw 0..1) x (cv 0..1): wave owns 32 q-rows and 64 output channels
// (ct in {2cv, 2cv+1}).
//
// r6 lesson: duplicating softmax across cv partners made flash VALU-bound
// (VALUBusy 52%, MfmaUtil 26%). Now wave cv computes softmax ONLY for its own
// 32-j half (t2=cv): 1 QK MFMA + 16 exp2 + 8 cvt_pk + 4 permlane, then
// exchanges bf16 pf fragments with its cv partner through LDS (contiguous
// 16B/lane stripes, conflict-free) and runs PV for BOTH halves. Halves the
// VALU+trans work per tile; +1 barrier and +4 LDS ops per tile.
__global__ __launch_bounds__(256, 2) void flash_kernel(
    const unsigned short* __restrict__ qb, const unsigned short* __restrict__ kb,
    const unsigned short* __restrict__ vt, const float* __restrict__ x,
    const float* __restrict__ gamma, float* __restrict__ out)
{
    __shared__ __align__(16) unsigned char smem[45568];
    unsigned short* sV = (unsigned short*)smem;              // [2][8192] us (16KB each)
    unsigned short* sK = (unsigned short*)(smem + 32768);    // [2][1024] us (2KB each)
    // pfx: 8 stripes of 64 lanes x 16B at 36864..45055 (stripe = w*2 + s1)
    // lb:  [4][32] floats at 45056..45567

    const int t = threadIdx.x;
    const int w = t >> 6, lane = t & 63;
    const int m31 = lane & 31, h = lane >> 5;
    const int mw = w >> 1, cv = w & 1;
    const int b  = blockIdx.x & 7;
    const int m0 = (blockIdx.x >> 3) * 64;
    const int mrow = m0 + 32 * mw;

    const unsigned short* vtile0 = vt + (size_t)b * (NTOK * 128);  // 16KB per jt tile, contiguous
    const unsigned short* ktile0 = kb + (size_t)b * (NTOK * 16);   // 2KB per jt tile, contiguous

    // Q B-frag: B[k=ch 8h+e][n=m31]; scale (incl. log2e) pre-folded into qb.
    const s16x8 qf = *(const s16x8*)(qb + ((size_t)b * NTOK + mrow + m31) * 16 + 8 * h);

    f32x16 O[2];   // 32 loop-carried acc regs (ct = 2cv + ci)
#pragma unroll
    for (int ci = 0; ci < 2; ++ci)
#pragma unroll
        for (int r = 0; r < 16; ++r) O[ci][r] = 0.f;
    float la0 = 0.f, la1 = 0.f, la2 = 0.f, la3 = 0.f;

    // stage tile jt_ into buffer d: V 16KB (4 calls/wave, 4KB each), K 2KB (waves 0,1)
#define STAGE(d, jt_) do {                                                          \
        const unsigned short* vs_ = vtile0 + (size_t)(jt_) * 8192 + w * 2048 + lane * 8; \
        gload16(vs_,        smem + (d) * 16384 + w * 4096);                         \
        gload16(vs_ + 512,  smem + (d) * 16384 + w * 4096 + 1024);                  \
        gload16(vs_ + 1024, smem + (d) * 16384 + w * 4096 + 2048);                  \
        gload16(vs_ + 1536, smem + (d) * 16384 + w * 4096 + 3072);                  \
        if (w < 2) {                                                                \
            const unsigned short* ks_ = ktile0 + (size_t)(jt_) * 1024 + w * 512 + lane * 8; \
            gload16(ks_, smem + 32768 + (d) * 2048 + w * 1024);                     \
        }                                                                           \
    } while (0)

    STAGE(0, 0);
    __syncthreads();   // drains vmcnt -> tile 0 resident

    int cur = 0;
    for (int jt = 0; jt < 64; ++jt) {
        if (jt < 63) STAGE(cur ^ 1, jt + 1);   // async; drained at barrier A below

        const unsigned short* sVc = sV + cur * 8192;
        const unsigned short* sKc = sK + cur * 1024;

        // K A-frag for OWN 32-j half only (t2 = cv): rows j-local = 32cv + m31
        const s16x8 kf = *(const s16x8*)(sKc + (size_t)(32 * cv + m31) * 16 + 8 * h);

        // scores: S^T (D[j][m]) for own half
        f32x16 sd;
#pragma unroll
        for (int r = 0; r < 16; ++r) sd[r] = 0.f;
        sd = __builtin_amdgcn_mfma_f32_32x32x16_bf16(kf, qf, sd, 0, 0, 0);

        // softmax numerator for own half: exp2 (scale folded), pack to bf16
        uint2 pk[4];
#pragma unroll
        for (int q = 0; q < 4; ++q) {
            const float e0 = EXP2F(sd[4 * q + 0]);
            const float e1 = EXP2F(sd[4 * q + 1]);
            const float e2 = EXP2F(sd[4 * q + 2]);
            const float e3 = EXP2F(sd[4 * q + 3]);
            la0 += e0; la1 += e1; la2 += e2; la3 += e3;
            pk[q].x = cvtpkbf(e0, e1);
            pk[q].y = cvtpkbf(e2, e3);
        }

        // register-only C->B transform via permlane32_swap (r2-verified)
        s16x8 pf[2];
#pragma unroll
        for (int s1 = 0; s1 < 2; ++s1) {
            const uint2 rx = plswap32(pk[2 * s1].x, pk[2 * s1 + 1].x);
            const uint2 ry = plswap32(pk[2 * s1].y, pk[2 * s1 + 1].y);
            union { s16x8 v; unsigned u[4]; } A;
            A.u[0] = rx.x; A.u[1] = ry.x; A.u[2] = rx.y; A.u[3] = ry.y;
            pf[s1] = A.v;
        }

        // publish own pf to the cv partner (contiguous 16B/lane, conflict-free)
        *(s16x8*)(smem + 36864 + (size_t)((w * 2 + 0) * 64 + lane) * 16) = pf[0];
        *(s16x8*)(smem + 36864 + (size_t)((w * 2 + 1) * 64 + lane) * 16) = pf[1];
        __syncthreads();   // barrier A: pf visible (also drains staging vmcnt)

        // partner's pf for the other half (issue loads early)
        const s16x8 pfp0 = *(const s16x8*)(smem + 36864 + (size_t)(((w ^ 1) * 2 + 0) * 64 + lane) * 16);
        const s16x8 pfp1 = *(const s16x8*)(smem + 36864 + (size_t)(((w ^ 1) * 2 + 1) * 64 + lane) * 16);

        // PV own half (t2 = cv), pf in registers
#pragma unroll
        for (int sl = 0; sl < 2; ++sl)
#pragma unroll
            for (int ci = 0; ci < 2; ++ci) {
                const s16x8 vfr = *(const s16x8*)(sVc + (2 * cv + sl) * 2048 + h * 1024 +
                                                  (2 * cv + ci) * 256 + m31 * 8);
                O[ci] = __builtin_amdgcn_mfma_f32_32x32x16_bf16(vfr, pf[sl], O[ci], 0, 0, 0);
            }
        // PV partner half (t2 = 1-cv), pf from LDS
#pragma unroll
        for (int sl = 0; sl < 2; ++sl)
#pragma unroll
            for (int ci = 0; ci < 2; ++ci) {
                const s16x8 vfr = *(const s16x8*)(sVc + (2 * (1 - cv) + sl) * 2048 + h * 1024 +
                                                  (2 * cv + ci) * 256 + m31 * 8);
                O[ci] = __builtin_amdgcn_mfma_f32_32x32x16_bf16(vfr, sl ? pfp1 : pfp0, O[ci], 0, 0, 0);
            }

        __syncthreads();   // barrier B: all reads of cur done; staged tile ready
        cur ^= 1;
    }
#undef STAGE

    // own-half l: h-lanes hold disjoint j subsets of the half
    float l_acc = (la0 + la1) + (la2 + la3);
    l_acc += __shfl_xor(l_acc, 32);

    // add cv-partner's half (same 32 q-rows)
    float* lb = (float*)(smem + 45056);
    if (lane < 32) lb[w * 32 + m31] = l_acc;
    __syncthreads();
    const float l_tot = l_acc + lb[(w ^ 1) * 32 + m31];

    const float linv = 1.f / l_tot;
    const float g = gamma[0];
#pragma unroll
    for (int ci = 0; ci < 2; ++ci) {
        const int ct = 2 * cv + ci;
#pragma unroll
        for (int r = 0; r < 16; ++r) {
            const int c = 32 * ct + (r & 3) + 8 * (r >> 2) + 4 * h;
            const size_t idx = ((size_t)b * 128 + c) * NTOK + mrow + m31;
            out[idx] = fmaf(g, O[ci][r] * linv, x[idx]);
        }
    }
}

extern "C" void kernel_launch(void* const* d_in, const int* in_sizes, int n_in,
                              void* d_out, int out_size, void* d_ws, size_t ws_size,
                              hipStream_t stream)
{
    const float* x     = (const float*)d_in[0];
    const float* Wq    = (const float*)d_in[1];
    const float* bq    = (const float*)d_in[2];
    const float* Wk    = (const float*)d_in[3];
    const float* bk    = (const float*)d_in[4];
    const float* Wv    = (const float*)d_in[5];
    const float* bv    = (const float*)d_in[6];
    const float* gamma = (const float*)d_in[7];
    float* out = (float*)d_out;

    // workspace (bf16 elements)
    unsigned short* qb  = (unsigned short*)d_ws;                 // 8*4096*16
    unsigned short* kb  = qb  + (size_t)NB_ * NTOK * 16;
    unsigned short* vt  = kb  + (size_t)NB_ * NTOK * 16;         // 8*128*4096 (fragment-major)
    unsigned short* wvb = vt  + (size_t)NB_ * 128 * NTOK;        // 128*128
    unsigned short* wqb = wvb + 16384;                           // 16*128
    unsigned short* wkb = wqb + 2048;

    wcvt_kernel<<<80, 256, 0, stream>>>(Wq, Wk, Wv, wvb, wqb, wkb);
    proj_kernel<<<512, 256, 0, stream>>>(x, wvb, wqb, wkb, bq, bk, bv, qb, kb, vt);
    flash_kernel<<<512, 256, 0, stream>>>(qb, kb, vt, x, gamma, out);
}

// Round 8
// 151.089 us; speedup vs baseline: 2.6527x; 1.0056x over previous
//
#include <hip/hip_runtime.h>
#include <cstddef>
#include <cstdint>

#define NTOK 4096
#define NB_  8

// 0.25 (=1/sqrt(Cq)) * log2(e): folded into q so flash can use raw exp2.
#define QSCALE 0.36067376022224085f

typedef float f32x4  __attribute__((ext_vector_type(4)));
typedef float f32x16 __attribute__((ext_vector_type(16)));
typedef short s16x8  __attribute__((ext_vector_type(8)));

#if __has_builtin(__builtin_amdgcn_exp2f)
#define EXP2F(x) __builtin_amdgcn_exp2f(x)
#else
#define EXP2F(x) exp2f(x)
#endif

static __device__ __forceinline__ unsigned short f2bf(float f) {
    unsigned u = __float_as_uint(f);
    unsigned r = (u + 0x7FFFu + ((u >> 16) & 1u)) >> 16;
    return (unsigned short)r;
}

// 2 f32 -> packed bf16 pair (low half = a), RNE.
static __device__ __forceinline__ unsigned cvtpkbf(float a, float b) {
    unsigned r;
    asm("v_cvt_pk_bf16_f32 %0, %1, %2" : "=v"(r) : "v"(a), "v"(b));
    return r;
}

// v_permlane32_swap_b32: ret.x = [a(lanes0-31) | b(lanes0-31)],
//                        ret.y = [a(lanes32-63) | b(lanes32-63)].
static __device__ __forceinline__ uint2 plswap32(unsigned a, unsigned b) {
#if __has_builtin(__builtin_amdgcn_permlane32_swap)
    auto r = __builtin_amdgcn_permlane32_swap((int)a, (int)b, false, false);
    return make_uint2((unsigned)r[0], (unsigned)r[1]);
#else
    const int xa = (((int)threadIdx.x & 63) ^ 32) << 2;
    const unsigned pa = (unsigned)__builtin_amdgcn_ds_bpermute(xa, (int)a);
    const unsigned pb = (unsigned)__builtin_amdgcn_ds_bpermute(xa, (int)b);
    const bool hi = (threadIdx.x & 32) != 0;
    return make_uint2(hi ? pb : a, hi ? b : pa);
#endif
}

// lane^16 exchange (within each 32-lane half): ds_swizzle BitMode xor=16
static __device__ __forceinline__ unsigned swz16(unsigned v) {
    return (unsigned)__builtin_amdgcn_ds_swizzle((int)v, 0x401F);
}

// async global(16B/lane) -> LDS(base + lane*16), wave-level
static __device__ __forceinline__ void gload16(const void* g, void* l) {
    __builtin_amdgcn_global_load_lds(
        (const __attribute__((address_space(1))) unsigned int*)g,
        (__attribute__((address_space(3))) unsigned int*)l, 16, 0, 0);
}

// ---------------- P0: weights fp32 -> bf16 ----------------
__global__ __launch_bounds__(256) void wcvt_kernel(
    const float* __restrict__ Wq, const float* __restrict__ Wk, const float* __restrict__ Wv,
    unsigned short* __restrict__ wvb, unsigned short* __restrict__ wqb,
    unsigned short* __restrict__ wkb)
{
    int i = blockIdx.x * 256 + threadIdx.x;  // 0..20479
    if (i < 16384)      wvb[i]         = f2bf(Wv[i]);
    else if (i < 18432) wqb[i - 16384] = f2bf(Wq[i - 16384]);
    else                wkb[i - 18432] = f2bf(Wk[i - 18432]);
}

// ---------------- P1: fused transpose + projections ----------------
// Flat grid 512 blocks; b = blk & 7 pins each batch to one XCD. V written in
// flash's fragment-major layout: v3[b][jt=j>>6][s=(j>>4)&3][h=(j>>3)&1][c][e=j&7].
// r7 lesson: uint2 V-stores at 16B stride are 50%-dense write segments (~2x HBM
// write traffic). Lanes l and l^16 hold e-halves 0-3/4-7 of the SAME channel
// row -> ds_swizzle(xor16) exchange assembles full 16B rows: even-g16 lanes
// store channel 32mp+c16, odd lanes 32mp+16+c16, as dense uint4.
__global__ __launch_bounds__(256) void proj_kernel(
    const float* __restrict__ x,
    const unsigned short* __restrict__ wvb, const unsigned short* __restrict__ wqb,
    const unsigned short* __restrict__ wkb,
    const float* __restrict__ bq, const float* __restrict__ bk, const float* __restrict__ bv,
    unsigned short* __restrict__ qb, unsigned short* __restrict__ kb,
    unsigned short* __restrict__ vt)
{
    __shared__ float lt[128][68];   // [c][n0..63], padded rows (16B-aligned stride)
    const int t = threadIdx.x;
    const int w = t >> 6, lane = t & 63;
    const int c16 = lane & 15, g16 = lane >> 4;
    const int b  = blockIdx.x & 7;
    const int n0 = (blockIdx.x >> 3) * 64;

    // stage x tile: 128 rows x 64 floats
    {
        const int n4 = t & 15;
#pragma unroll
        for (int pass = 0; pass < 8; ++pass) {
            const int c = (t >> 4) + 16 * pass;
            const float4 val = ((const float4*)(x + ((size_t)b * 128 + c) * NTOK + n0))[n4];
            *(float4*)&lt[c][n4 * 4] = val;
        }
    }
    __syncthreads();

    // xf fragments for this wave's 16 tokens (token = n0 + 16w + c16)
    const int nl = 16 * w + c16;
    s16x8 xf[4];
#pragma unroll
    for (int kc = 0; kc < 4; ++kc) {
        unsigned rr[8];
#pragma unroll
        for (int i = 0; i < 8; ++i) {
            const unsigned u = __float_as_uint(lt[32 * kc + 8 * g16 + i][nl]);
            rr[i] = u + 0x7FFFu + ((u >> 16) & 1u);
        }
        union { s16x8 v; unsigned u[4]; } cvt;
#pragma unroll
        for (int d = 0; d < 4; ++d)
            cvt.u[d] = __builtin_amdgcn_perm(rr[2 * d + 1], rr[2 * d], 0x07060302u);
        xf[kc] = cvt.v;
    }

    // ---- V = Wv * X  (fragment-major, 16B-dense stores) ----
    // mfma(xf, wf): D[m=token 4g16+r][n=c_out]. token j = n0+16w+4g16+r:
    // s=w, h=g16>>1, e=4(g16&1)+r. Pair (g16, g16^1) = full e-row of channel.
    unsigned short* vwp16 = vt + (size_t)b * (NTOK * 128) +
                            (size_t)(((n0 >> 6) * 8) + 2 * w + (g16 >> 1)) * 1024;
    const bool oddg = (g16 & 1) != 0;
#pragma unroll
    for (int mp = 0; mp < 4; ++mp) {
        f32x4 accA = {0.f, 0.f, 0.f, 0.f}, accB = {0.f, 0.f, 0.f, 0.f};
#pragma unroll
        for (int kc = 0; kc < 4; ++kc) {
            const s16x8 wfA = *(const s16x8*)(wvb + (size_t)(32 * mp      + c16) * 128 + 32 * kc + 8 * g16);
            const s16x8 wfB = *(const s16x8*)(wvb + (size_t)(32 * mp + 16 + c16) * 128 + 32 * kc + 8 * g16);
            accA = __builtin_amdgcn_mfma_f32_16x16x32_bf16(xf[kc], wfA, accA, 0, 0, 0);
            accB = __builtin_amdgcn_mfma_f32_16x16x32_bf16(xf[kc], wfB, accB, 0, 0, 0);
        }
        const float bvA = bv[32 * mp + c16], bvB = bv[32 * mp + 16 + c16];
        uint2 A, B;
        A.x = cvtpkbf(accA[0] + bvA, accA[1] + bvA);
        A.y = cvtpkbf(accA[2] + bvA, accA[3] + bvA);
        B.x = cvtpkbf(accB[0] + bvB, accB[1] + bvB);
        B.y = cvtpkbf(accB[2] + bvB, accB[3] + bvB);
        // exchange with lane^16: even lane keeps channel A row (needs partner A),
        // odd lane keeps channel B row (needs partner B).
        const unsigned s0 = swz16(oddg ? A.x : B.x);
        const unsigned s1 = swz16(oddg ? A.y : B.y);
        uint4 W;
        W.x = oddg ? s0 : A.x;
        W.y = oddg ? s1 : A.y;
        W.z = oddg ? B.x : s0;
        W.w = oddg ? B.y : s1;
        const int crow = 32 * mp + (oddg ? 16 : 0) + c16;
        *(uint4*)(vwp16 + (size_t)crow * 8) = W;
    }
    // ---- Q, K ----
    // mfma(wqf, xf): D[m=qch 4g16+r][n=token c16] -> 4 consecutive qch per thread.
    f32x4 aq = {0.f, 0.f, 0.f, 0.f}, ak = {0.f, 0.f, 0.f, 0.f};
#pragma unroll
    for (int kc = 0; kc < 4; ++kc) {
        const s16x8 wqf = *(const s16x8*)(wqb + (size_t)c16 * 128 + 32 * kc + 8 * g16);
        const s16x8 wkf = *(const s16x8*)(wkb + (size_t)c16 * 128 + 32 * kc + 8 * g16);
        aq = __builtin_amdgcn_mfma_f32_16x16x32_bf16(wqf, xf[kc], aq, 0, 0, 0);
        ak = __builtin_amdgcn_mfma_f32_16x16x32_bf16(wkf, xf[kc], ak, 0, 0, 0);
    }
    const float4 bq4 = *(const float4*)(bq + 4 * g16);
    const float4 bk4 = *(const float4*)(bk + 4 * g16);
    const int n = n0 + 16 * w + c16;
    uint2 pq, pkk;
    pq.x  = cvtpkbf(QSCALE * (aq[0] + bq4.x), QSCALE * (aq[1] + bq4.y));
    pq.y  = cvtpkbf(QSCALE * (aq[2] + bq4.z), QSCALE * (aq[3] + bq4.w));
    pkk.x = cvtpkbf(ak[0] + bk4.x, ak[1] + bk4.y);
    pkk.y = cvtpkbf(ak[2] + bk4.z, ak[3] + bk4.w);
    *(uint2*)(qb + ((size_t)b * NTOK + n) * 16 + 4 * g16) = pq;
    *(uint2*)(kb + ((size_t)b * NTOK + n) * 16 + 4 * g16) = pkk;
}

// ---------------- P2: flash attention, pipelined single-barrier loop ----------
// Grid 512 blocks (2/CU): b = blk & 7 (XCD-pinned batch), m-tile = blk>>3 (64 q rows).
// 4 waves = (mw 0..1) x (cv 0..1): wave owns 32 q-rows + 64 output channels.
//
// r7 lesson: 2 barriers/tile + a serial per-tile chain made flash latency-bound
// (2540 cyc/tile vs ~300 cyc work; MfmaUtil 23%). Now softmax is pipelined one
// tile ahead: iteration jt does PV[jt] (own pf regs + partner pf from LDS, set
// jt&1) AND QK+softmax[jt+1] (writes pf set (jt+1)&1), with ONE barrier. K is
// triple-buffered (staged 2 ahead, needed by the early QK), V double-buffered.
// All buffer parities are disjoint within an iteration; the single barrier
// iteration-locks all waves, so there are no cross-iteration races.
__global__ __launch_bounds__(256, 2) void flash_kernel(
    const unsigned short* __restrict__ qb, const unsigned short* __restrict__ kb,
    const unsigned short* __restrict__ vt, const float* __restrict__ x,
    const float* __restrict__ gamma, float* __restrict__ out)
{
    // layout: sV [2][16384]B @0; sK [3][2048]B @32768; pf [2 sets][8 stripes][1024]B @38912; lb @55296
    __shared__ __align__(16) unsigned char smem[55808];

    const int t = threadIdx.x;
    const int w = t >> 6, lane = t & 63;
    const int m31 = lane & 31, h = lane >> 5;
    const int mw = w >> 1, cv = w & 1;
    const int b  = blockIdx.x & 7;
    const int m0 = (blockIdx.x >> 3) * 64;
    const int mrow = m0 + 32 * mw;

    const unsigned short* vtile0 = vt + (size_t)b * (NTOK * 128);  // 16KB per jt tile
    const unsigned short* ktile0 = kb + (size_t)b * (NTOK * 16);   // 2KB per jt tile

    // Q B-frag: B[k=ch 8h+e][n=m31]; scale (incl. log2e) pre-folded into qb.
    const s16x8 qf = *(const s16x8*)(qb + ((size_t)b * NTOK + mrow + m31) * 16 + 8 * h);

    f32x16 O[2];   // 32 loop-carried acc regs (ct = 2cv + ci)
#pragma unroll
    for (int ci = 0; ci < 2; ++ci)
#pragma unroll
        for (int r = 0; r < 16; ++r) O[ci][r] = 0.f;
    float la0 = 0.f, la1 = 0.f, la2 = 0.f, la3 = 0.f;

#define STAGE_V(d, jt_) do {                                                        \
        const unsigned short* vs_ = vtile0 + (size_t)(jt_) * 8192 + w * 2048 + lane * 8; \
        gload16(vs_,        smem + (d) * 16384 + w * 4096);                         \
        gload16(vs_ + 512,  smem + (d) * 16384 + w * 4096 + 1024);                  \
        gload16(vs_ + 1024, smem + (d) * 16384 + w * 4096 + 2048);                  \
        gload16(vs_ + 1536, smem + (d) * 16384 + w * 4096 + 3072);                  \
    } while (0)

#define STAGE_K(d, jt_) do {                                                        \
        if (w < 2) {                                                                \
            const unsigned short* ks_ = ktile0 + (size_t)(jt_) * 1024 + w * 512 + lane * 8; \
            gload16(ks_, smem + 32768 + (d) * 2048 + w * 1024);                     \
        }                                                                           \
    } while (0)

    // QK + softmax for own 32-j half (t2=cv) of one tile; fills PF_ and
    // publishes it to this wave's LDS stripes (set_).
#define SOFTMAX(kd_, set_, PF_) do {                                                \
        const s16x8 kf_ = *(const s16x8*)((const unsigned short*)(smem + 32768 + (kd_) * 2048) + \
                                          (size_t)(32 * cv + m31) * 16 + 8 * h);    \
        f32x16 sd_;                                                                 \
        _Pragma("unroll") for (int r_ = 0; r_ < 16; ++r_) sd_[r_] = 0.f;            \
        sd_ = __builtin_amdgcn_mfma_f32_32x32x16_bf16(kf_, qf, sd_, 0, 0, 0);       \
        uint2 pk_[4];                                                               \
        _Pragma("unroll") for (int q_ = 0; q_ < 4; ++q_) {                          \
            const float e0_ = EXP2F(sd_[4 * q_ + 0]);                               \
            const float e1_ = EXP2F(sd_[4 * q_ + 1]);                               \
            const float e2_ = EXP2F(sd_[4 * q_ + 2]);                               \
            const float e3_ = EXP2F(sd_[4 * q_ + 3]);                               \
            la0 += e0_; la1 += e1_; la2 += e2_; la3 += e3_;                         \
            pk_[q_].x = cvtpkbf(e0_, e1_);                                          \
            pk_[q_].y = cvtpkbf(e2_, e3_);                                          \
        }                                                                           \
        _Pragma("unroll") for (int s1_ = 0; s1_ < 2; ++s1_) {                       \
            const uint2 rx_ = plswap32(pk_[2 * s1_].x, pk_[2 * s1_ + 1].x);         \
            const uint2 ry_ = plswap32(pk_[2 * s1_].y, pk_[2 * s1_ + 1].y);         \
            union { s16x8 v; unsigned u[4]; } A_;                                   \
            A_.u[0] = rx_.x; A_.u[1] = ry_.x; A_.u[2] = rx_.y; A_.u[3] = ry_.y;     \
            PF_[s1_] = A_.v;                                                        \
            *(s16x8*)(smem + 38912 + (set_) * 8192 + (w * 2 + s1_) * 1024 + lane * 16) = PF_[s1_]; \
        }                                                                           \
    } while (0)

    s16x8 pfA[2];

    // prologue: V0, K0, K1 staged; softmax tile 0 -> pf set 0
    STAGE_V(0, 0);
    STAGE_K(0, 0);
    STAGE_K(1, 1);
    __syncthreads();                 // tiles resident (vmcnt drained)
    SOFTMAX(0, 0, pfA);
    __syncthreads();                 // pf set 0 visible to partner

    for (int jt = 0; jt < 64; ++jt) {
        if (jt < 63) STAGE_V((jt + 1) & 1, jt + 1);
        if (jt < 62) STAGE_K((jt + 2) % 3, jt + 2);

        const unsigned short* sVc = (const unsigned short*)smem + (jt & 1) * 8192;
        const int set = jt & 1;
        const s16x8 pfp0 = *(const s16x8*)(smem + 38912 + set * 8192 + ((w ^ 1) * 2 + 0) * 1024 + lane * 16);
        const s16x8 pfp1 = *(const s16x8*)(smem + 38912 + set * 8192 + ((w ^ 1) * 2 + 1) * 1024 + lane * 16);

        // PV own half (t2 = cv), pf in registers
#pragma unroll
        for (int sl = 0; sl < 2; ++sl)
#pragma unroll
            for (int ci = 0; ci < 2; ++ci) {
                const s16x8 vfr = *(const s16x8*)(sVc + (2 * cv + sl) * 2048 + h * 1024 +
                                                  (2 * cv + ci) * 256 + m31 * 8);
                O[ci] = __builtin_amdgcn_mfma_f32_32x32x16_bf16(vfr, pfA[sl], O[ci], 0, 0, 0);
            }
        // PV partner half (t2 = 1-cv), pf from LDS
#pragma unroll
        for (int sl = 0; sl < 2; ++sl)
#pragma unroll
            for (int ci = 0; ci < 2; ++ci) {
                const s16x8 vfr = *(const s16x8*)(sVc + (2 * (1 - cv) + sl) * 2048 + h * 1024 +
                                                  (2 * cv + ci) * 256 + m31 * 8);
                O[ci] = __builtin_amdgcn_mfma_f32_32x32x16_bf16(vfr, sl ? pfp1 : pfp0, O[ci], 0, 0, 0);
            }

        // softmax for next tile (overlaps PV in the same barrier-free region)
        if (jt < 63) SOFTMAX((jt + 1) % 3, (jt + 1) & 1, pfA);

        __syncthreads();
    }
#undef STAGE_V
#undef STAGE_K
#undef SOFTMAX

    // own-half l: h-lanes hold disjoint j subsets of the half
    float l_acc = (la0 + la1) + (la2 + la3);
    l_acc += __shfl_xor(l_acc, 32);

    // add cv-partner's half (same 32 q-rows)
    float* lb = (float*)(smem + 55296);
    if (lane < 32) lb[w * 32 + m31] = l_acc;
    __syncthreads();
    const float l_tot = l_acc + lb[(w ^ 1) * 32 + m31];

    const float linv = 1.f / l_tot;
    const float g = gamma[0];
#pragma unroll
    for (int ci = 0; ci < 2; ++ci) {
        const int ct = 2 * cv + ci;
#pragma unroll
        for (int r = 0; r < 16; ++r) {
            const int c = 32 * ct + (r & 3) + 8 * (r >> 2) + 4 * h;
            const size_t idx = ((size_t)b * 128 + c) * NTOK + mrow + m31;
            out[idx] = fmaf(g, O[ci][r] * linv, x[idx]);
        }
    }
}

extern "C" void kernel_launch(void* const* d_in, const int* in_sizes, int n_in,
                              void* d_out, int out_size, void* d_ws, size_t ws_size,
                              hipStream_t stream)
{
    const float* x     = (const float*)d_in[0];
    const float* Wq    = (const float*)d_in[1];
    const float* bq    = (const float*)d_in[2];
    const float* Wk    = (const float*)d_in[3];
    const float* bk    = (const float*)d_in[4];
    const float* Wv    = (const float*)d_in[5];
    const float* bv    = (const float*)d_in[6];
    const float* gamma = (const float*)d_in[7];
    float* out = (float*)d_out;

    // workspace (bf16 elements)
    unsigned short* qb  = (unsigned short*)d_ws;                 // 8*4096*16
    unsigned short* kb  = qb  + (size_t)NB_ * NTOK * 16;
    unsigned short* vt  = kb  + (size_t)NB_ * NTOK * 16;         // 8*128*4096 (fragment-major)
    unsigned short* wvb = vt  + (size_t)NB_ * 128 * NTOK;        // 128*128
    unsigned short* wqb = wvb + 16384;                           // 16*128
    unsigned short* wkb = wqb + 2048;

    wcvt_kernel<<<80, 256, 0, stream>>>(Wq, Wk, Wv, wvb, wqb, wkb);
    proj_kernel<<<512, 256, 0, stream>>>(x, wvb, wqb, wkb, bq, bk, bv, qb, kb, vt);
    flash_kernel<<<512, 256, 0, stream>>>(qb, kb, vt, x, gamma, out);
}